// Round 1
// baseline (366.706 us; speedup 1.0000x reference)
//
#include <hip/hip_runtime.h>

// SparseCodebook: out[b] = min_k mean_d |codes[b,d] - centroids[cls[b],k,d]|
// B=262144, NUM_CLASSES=1000, K=4, D=256.
// Memory-bound: codes stream = 256 MiB (HBM), centroids 4.1 MB (L2-resident).
// One wave (64 lanes) per sample; lane i holds float4 = dims [4i, 4i+4).

#define B_TOTAL     262144
#define NUM_CLASSES 1000
#define KC          4
#define DIM         256

__global__ __launch_bounds__(256) void sparse_codebook_kernel(
    const float* __restrict__ codes,
    const int*   __restrict__ pred_class,
    const float* __restrict__ centroids,
    float*       __restrict__ out)
{
    const int tid    = blockIdx.x * blockDim.x + threadIdx.x;
    const int sample = tid >> 6;          // one wave per sample
    const int lane   = threadIdx.x & 63;
    if (sample >= B_TOTAL) return;

    // wave-uniform class index; readfirstlane encourages SGPR addressing
    const int cls = __builtin_amdgcn_readfirstlane(pred_class[sample]);

    // coalesced 16B/lane load of this sample's code row (64 float4 = 256 floats)
    const float4* codes4 = (const float4*)codes + (size_t)sample * 64;
    const float4  c      = codes4[lane];

    // 4 centroid rows of this class; contiguous, L2-resident
    const float4* cent4 = (const float4*)centroids + (size_t)cls * (KC * DIM / 4);

    float s[KC];
#pragma unroll
    for (int k = 0; k < KC; ++k) {
        const float4 g = cent4[k * 64 + lane];
        s[k] = fabsf(c.x - g.x) + fabsf(c.y - g.y)
             + fabsf(c.z - g.z) + fabsf(c.w - g.w);
    }

    // butterfly reduction across the 64-lane wave for all 4 sums
#pragma unroll
    for (int off = 32; off > 0; off >>= 1) {
#pragma unroll
        for (int k = 0; k < KC; ++k)
            s[k] += __shfl_xor(s[k], off, 64);
    }

    if (lane == 0) {
        const float m = fminf(fminf(s[0], s[1]), fminf(s[2], s[3]));
        out[sample] = m * (1.0f / (float)DIM);
    }
}

extern "C" void kernel_launch(void* const* d_in, const int* in_sizes, int n_in,
                              void* d_out, int out_size, void* d_ws, size_t ws_size,
                              hipStream_t stream) {
    const float* codes = (const float*)d_in[0];
    const int*   pred  = (const int*)d_in[1];
    const float* cents = (const float*)d_in[2];
    float*       out   = (float*)d_out;

    // one wave per sample -> B*64 threads; 256-thread blocks
    const int total_threads = B_TOTAL * 64;
    const int block = 256;
    const int grid  = total_threads / block;  // 65536
    sparse_codebook_kernel<<<grid, block, 0, stream>>>(codes, pred, cents, out);
}